// Round 3
// baseline (180.453 us; speedup 1.0000x reference)
//
#include <hip/hip_runtime.h>
#include <hip/hip_bf16.h>
#include <cstdint>

// LSTM cell: g[g,b,n] = sum_k A[b,k] * Wcat[g,k,n],  A = [x | h]  (K = 2048)
// i,f,o = sigmoid(g0,1,2), u = tanh(g3), c_t = i*u + f*c, h_t = o*tanh(c_t)
// Round 3: 8-phase 256^2 schedule (T1+T2+T3+T4+T5), gate-bundled B so the
// LSTM epilogue stays fused. BM=256, BN_eff=4x64, BK=64, 8 waves.

#define LDS_TOTAL 131072    // 2 buf x (A 32KB + B 32KB)

typedef __attribute__((ext_vector_type(8))) short bf16x8;   // 8 bf16 = 4 VGPR
typedef __attribute__((ext_vector_type(4))) float f32x4;
typedef __attribute__((ext_vector_type(4))) unsigned int u32x4;

static __device__ __forceinline__ unsigned short f2bf(float f) {
  union { float f; unsigned int u; } v; v.f = f;
  unsigned int u = v.u;
  unsigned int r = (u + 0x7FFFu + ((u >> 16) & 1u)) >> 16;  // RTN-even
  return (unsigned short)r;
}

static __device__ __forceinline__ void load16(const void* gp, void* lp) {
  __builtin_amdgcn_global_load_lds(
      (const __attribute__((address_space(1))) void*)gp,
      (__attribute__((address_space(3))) void*)lp, 16, 0, 0);
}

static __device__ __forceinline__ float sigmoid_f(float x) {
  return 1.0f / (1.0f + __expf(-x));
}
static __device__ __forceinline__ float tanh_f(float x) {
  float e = __expf(-2.0f * fabsf(x));
  float r = (1.0f - e) / (1.0f + e);
  return copysignf(r, x);
}

// ---- prep 1: pack A = [x | h] as bf16 [8192][2048] ----
__global__ __launch_bounds__(256) void pack_a_kernel(
    const float* __restrict__ x, const float* __restrict__ h,
    unsigned short* __restrict__ Apack) {
  int t = blockIdx.x * 256 + threadIdx.x;
  size_t base = (size_t)t * 8;
  int b = (int)(base >> 11);
  int k = (int)(base & 2047);
  const float* src = (k < 1024) ? (x + (size_t)b * 1024 + k)
                                : (h + (size_t)b * 1024 + (k - 1024));
  float4 v0 = ((const float4*)src)[0];
  float4 v1 = ((const float4*)src)[1];
  union { unsigned short s[8]; u32x4 v; } o;
  o.s[0] = f2bf(v0.x); o.s[1] = f2bf(v0.y); o.s[2] = f2bf(v0.z); o.s[3] = f2bf(v0.w);
  o.s[4] = f2bf(v1.x); o.s[5] = f2bf(v1.y); o.s[6] = f2bf(v1.z); o.s[7] = f2bf(v1.w);
  *(u32x4*)(Apack + base) = o.v;
}

// ---- prep 2: Wt[g][n][k] = bf16( k<1024 ? Wx[g][k][n] : Wh[g][k-1024][n] ) ----
__global__ __launch_bounds__(256) void prep_w_kernel(
    const float* __restrict__ Wx, const float* __restrict__ Wh,
    unsigned short* __restrict__ Wt) {
  __shared__ float tile[32][33];
  int bid = blockIdx.x;
  int g = bid >> 11;
  int rem = bid & 2047;
  int kt = rem >> 5;
  int nt = rem & 31;
  int k0 = kt * 32, n0 = nt * 32;
  int tx = threadIdx.x & 31, ty = threadIdx.x >> 5;
  const float* Wsrc;
  int ks;
  if (k0 < 1024) { Wsrc = Wx + (size_t)g * 1048576; ks = k0; }
  else           { Wsrc = Wh + (size_t)g * 1048576; ks = k0 - 1024; }
  #pragma unroll
  for (int s = 0; s < 4; ++s) {
    int r = ty + s * 8;
    tile[r][tx] = Wsrc[(size_t)(ks + r) * 1024 + n0 + tx];
  }
  __syncthreads();
  #pragma unroll
  for (int s = 0; s < 4; ++s) {
    int r = ty + s * 8;
    Wt[(size_t)((g << 10) + n0 + r) * 2048 + k0 + tx] = f2bf(tile[tx][r]);
  }
}

// ---- main: fused 4-gate GEMM, 8-phase schedule ----
// 512 thr = 8 waves (wr=w>>2 in {0,1}: rows wr*128..+128; wc=w&3: n wc*16..+16
// per gate). Buf (64KB): A[256][64] @0 (halves A0 rows 0-127, A1 128-255),
// B[4][64][64] @32768 (halves B0 g0-1, B1 g2-3). Stages lead reads by 4-7
// phases; one vmcnt(6) per K-step at P4 (T4); setprio around MFMA (T5).
__global__ __launch_bounds__(512, 2) void lstm_gemm_kernel(
    const unsigned short* __restrict__ Apack,   // [8192][2048] bf16
    const unsigned short* __restrict__ Wt,      // [4][1024][2048] bf16 (B^T)
    const float* __restrict__ cprev,
    float* __restrict__ out) {
  extern __shared__ char lds[];
  const int tid = threadIdx.x;
  const int l = tid & 63;
  const int w = tid >> 6;
  const int wr = w >> 2;
  const int wc = w & 3;
  const int bid0 = blockIdx.x;
  const int bid = (bid0 & 7) * 64 + (bid0 >> 3);   // XCD chunk swizzle (512%8==0)
  const int mt = bid >> 4;             // 32 m-tiles
  const int nt = bid & 15;             // 16 n-tiles
  const int m0 = mt << 8;
  const int n0 = nt << 6;

  char* const buf0 = lds;
  char* const buf1 = lds + 65536;

  f32x4 acc[8][4];                     // [m-frag][gate]
  #pragma unroll
  for (int mf = 0; mf < 8; ++mf)
    #pragma unroll
    for (int g = 0; g < 4; ++g) acc[mf][g] = (f32x4)0.0f;

  bf16x8 aR[4][2];                     // current m-half frags [i][kk]
  bf16x8 bR[4][2];                     // all gates [g][kk]

  const int lr = l & 15;
  const int kgrp = (l >> 4) << 4;      // 0/16/32/48 byte k-group
  const int sx = (lr & 7) << 4;        // XOR swizzle (row&7 == lr&7 everywhere)
  const int aoff = (wr * 128 + lr) * 128;
  const int boff = 32768 + (wc * 16 + lr) * 128;

  // Stage one 16KB half-tile (2 x load16/thread). Linear LDS dest,
  // inverse-XOR-swizzled global source (both-sides rule).
  auto stageA = [&](char* bufb, int h, int kstep) {
    const int k0 = kstep << 6;
    #pragma unroll
    for (int j = 0; j < 2; ++j) {
      int c = j * 512 + tid;
      int byt = c << 4;
      int rl = byt >> 7;                         // 0..127
      int kb = (byt & 127) ^ ((rl & 7) << 4);
      const unsigned short* gp =
          Apack + (size_t)(m0 + h * 128 + rl) * 2048 + k0 + (kb >> 1);
      load16(gp, bufb + h * 16384 + ((c & ~63) << 4));
    }
  };
  auto stageB = [&](char* bufb, int h, int kstep) {
    const int k0 = kstep << 6;
    #pragma unroll
    for (int j = 0; j < 2; ++j) {
      int c = j * 512 + tid;
      int byt = c << 4;
      int g = 2 * h + (byt >> 13);
      int loc = byt & 8191;
      int rl = loc >> 7;                         // 0..63 (n within gate)
      int kb = (loc & 127) ^ ((rl & 7) << 4);
      const unsigned short* gp =
          Wt + (size_t)((g << 10) + n0 + rl) * 2048 + k0 + (kb >> 1);
      load16(gp, bufb + 32768 + h * 16384 + ((c & ~63) << 4));
    }
  };

  auto readA = [&](const char* bufc, int mh) {   // 8 ds_read_b128
    #pragma unroll
    for (int i = 0; i < 4; ++i)
      #pragma unroll
      for (int kk = 0; kk < 2; ++kk)
        aR[i][kk] = *(const bf16x8*)(bufc + aoff + (mh * 64 + i * 16) * 128 +
                                     ((kk * 64 + kgrp) ^ sx));
  };
  auto readB = [&](const char* bufc, int gh) {   // 4 ds_read_b128
    #pragma unroll
    for (int i = 0; i < 2; ++i)
      #pragma unroll
      for (int kk = 0; kk < 2; ++kk)
        bR[gh * 2 + i][kk] = *(const bf16x8*)(bufc + boff + (gh * 2 + i) * 8192 +
                                              ((kk * 64 + kgrp) ^ sx));
  };
  auto mfma16 = [&](int mh, int gh) {            // one C-quadrant x K=64
    __builtin_amdgcn_s_setprio(1);
    #pragma unroll
    for (int kk = 0; kk < 2; ++kk)
      #pragma unroll
      for (int i = 0; i < 4; ++i)
        #pragma unroll
        for (int gg = 0; gg < 2; ++gg)
          acc[mh * 4 + i][gh * 2 + gg] = __builtin_amdgcn_mfma_f32_16x16x32_bf16(
              aR[i][kk], bR[gh * 2 + gg][kk], acc[mh * 4 + i][gh * 2 + gg], 0, 0, 0);
    __builtin_amdgcn_s_setprio(0);
  };

  // Prologue: stage t=0's 4 halves + t=1's {B0,B1,A0}; vmcnt(6) -> t=0 landed.
  stageA(buf0, 0, 0); stageA(buf0, 1, 0);
  stageB(buf0, 0, 0); stageB(buf0, 1, 0);
  stageB(buf1, 0, 1); stageB(buf1, 1, 1);
  stageA(buf1, 0, 1);
  asm volatile("s_waitcnt vmcnt(6)" ::: "memory");
  __builtin_amdgcn_sched_barrier(0);
  __builtin_amdgcn_s_barrier();

  auto kstep = [&](int t, char* bufc, char* bufn) {
    // ---- P1: quad (mh0, gh0) ----
    readA(bufc, 0);
    readB(bufc, 0);
    if (t + 1 < 32) stageA(bufn, 1, t + 1);      // A1(t+1)
    asm volatile("s_waitcnt lgkmcnt(8)" ::: "memory");
    __builtin_amdgcn_s_barrier();
    asm volatile("s_waitcnt lgkmcnt(0)" ::: "memory");
    __builtin_amdgcn_sched_barrier(0);
    mfma16(0, 0);
    __builtin_amdgcn_s_barrier();
    // ---- P2: quad (mh0, gh1) ----
    readB(bufc, 1);
    if (t + 2 < 32) stageB(bufc, 0, t + 2);      // B0(t+2): B0 read done @P1
    __builtin_amdgcn_s_barrier();
    asm volatile("s_waitcnt lgkmcnt(0)" ::: "memory");
    __builtin_amdgcn_sched_barrier(0);
    mfma16(0, 1);
    __builtin_amdgcn_s_barrier();
    // ---- P3: quad (mh1, gh1) ----
    readA(bufc, 1);
    if (t + 2 < 32) stageB(bufc, 1, t + 2);      // B1(t+2): B1 read done @P2
    __builtin_amdgcn_s_barrier();
    asm volatile("s_waitcnt lgkmcnt(0)" ::: "memory");
    __builtin_amdgcn_sched_barrier(0);
    mfma16(1, 1);
    __builtin_amdgcn_s_barrier();
    // ---- P4: quad (mh1, gh0) ---- (no new ds_reads; bR[g0,g1] kept from P1)
    if (t + 2 < 32) stageA(bufc, 0, t + 2);      // A0(t+2): A0 reads done @P3
    if (t < 30) asm volatile("s_waitcnt vmcnt(6)" ::: "memory");
    else        asm volatile("s_waitcnt vmcnt(0)" ::: "memory");
    __builtin_amdgcn_sched_barrier(0);
    __builtin_amdgcn_s_barrier();                // all waves: t+1 halves landed
    mfma16(1, 0);
    __builtin_amdgcn_s_barrier();
  };

  #pragma unroll 1
  for (int tt = 0; tt < 16; ++tt) {
    kstep(2 * tt,     buf0, buf1);
    kstep(2 * tt + 1, buf1, buf0);
  }

  // Epilogue: C/D layout col = lane&15, row = (lane>>4)*4 + reg  [m89]
  const int q = (l >> 4) << 2;
  const int col = n0 + wc * 16 + lr;
  #pragma unroll
  for (int mf = 0; mf < 8; ++mf) {
    #pragma unroll
    for (int j = 0; j < 4; ++j) {
      int row = m0 + wr * 128 + mf * 16 + q + j;
      float gi = acc[mf][0][j];
      float gf = acc[mf][1][j];
      float go = acc[mf][2][j];
      float gu = acc[mf][3][j];
      float i_ = sigmoid_f(gi);
      float f_ = sigmoid_f(gf);
      float o_ = sigmoid_f(go);
      float u_ = tanh_f(gu);
      size_t idx = (size_t)row * 1024 + col;
      float ct = i_ * u_ + f_ * cprev[idx];
      float ht = o_ * tanh_f(ct);
      out[idx] = ht;                   // h_t
      out[8388608 + idx] = ct;         // c_t
    }
  }
}

extern "C" void kernel_launch(void* const* d_in, const int* in_sizes, int n_in,
                              void* d_out, int out_size, void* d_ws, size_t ws_size,
                              hipStream_t stream) {
  const float* x  = (const float*)d_in[0];
  const float* h  = (const float*)d_in[1];
  const float* c  = (const float*)d_in[2];
  const float* Wx = (const float*)d_in[3];
  const float* Wh = (const float*)d_in[4];
  float* out = (float*)d_out;

  unsigned short* Apack = (unsigned short*)d_ws;                  // 33,554,432 B
  unsigned short* Wt = (unsigned short*)((char*)d_ws + 33554432); // 16,777,216 B

  hipFuncSetAttribute((const void*)lstm_gemm_kernel,
                      hipFuncAttributeMaxDynamicSharedMemorySize, LDS_TOTAL);

  pack_a_kernel<<<8192, 256, 0, stream>>>(x, h, Apack);
  prep_w_kernel<<<8192, 256, 0, stream>>>(Wx, Wh, Wt);
  lstm_gemm_kernel<<<dim3(512), dim3(512), LDS_TOTAL, stream>>>(Apack, Wt, c, out);
}

// Round 5
// 158.715 us; speedup vs baseline: 1.1370x; 1.1370x over previous
//
#include <hip/hip_runtime.h>
#include <hip/hip_bf16.h>
#include <cstdint>

// LSTM cell: g[g,b,n] = sum_k A[b,k] * Wcat[g,k,n],  A = [x | h]  (K = 2048)
// i,f,o = sigmoid(g0,1,2), u = tanh(g3), c_t = i*u + f*c, h_t = o*tanh(c_t)
// Round 5: round-4 (de-pinned 8-phase + hoisted stage bases) with the
// stageA half-stride fixed: h advances 128 rows = 262144 elements (was
// erroneously 131072 = the 64-row j-stride).

#define LDS_TOTAL 131072    // 2 buf x (A 32KB + B 32KB)

typedef __attribute__((ext_vector_type(8))) short bf16x8;   // 8 bf16 = 4 VGPR
typedef __attribute__((ext_vector_type(4))) float f32x4;
typedef __attribute__((ext_vector_type(4))) unsigned int u32x4;

static __device__ __forceinline__ unsigned short f2bf(float f) {
  union { float f; unsigned int u; } v; v.f = f;
  unsigned int u = v.u;
  unsigned int r = (u + 0x7FFFu + ((u >> 16) & 1u)) >> 16;  // RTN-even
  return (unsigned short)r;
}

static __device__ __forceinline__ void load16(const void* gp, void* lp) {
  __builtin_amdgcn_global_load_lds(
      (const __attribute__((address_space(1))) void*)gp,
      (__attribute__((address_space(3))) void*)lp, 16, 0, 0);
}

static __device__ __forceinline__ float sigmoid_f(float x) {
  return 1.0f / (1.0f + __expf(-x));
}
static __device__ __forceinline__ float tanh_f(float x) {
  float e = __expf(-2.0f * fabsf(x));
  float r = (1.0f - e) / (1.0f + e);
  return copysignf(r, x);
}

// ---- prep 1: pack A = [x | h] as bf16 [8192][2048] ----
__global__ __launch_bounds__(256) void pack_a_kernel(
    const float* __restrict__ x, const float* __restrict__ h,
    unsigned short* __restrict__ Apack) {
  int t = blockIdx.x * 256 + threadIdx.x;
  size_t base = (size_t)t * 8;
  int b = (int)(base >> 11);
  int k = (int)(base & 2047);
  const float* src = (k < 1024) ? (x + (size_t)b * 1024 + k)
                                : (h + (size_t)b * 1024 + (k - 1024));
  float4 v0 = ((const float4*)src)[0];
  float4 v1 = ((const float4*)src)[1];
  union { unsigned short s[8]; u32x4 v; } o;
  o.s[0] = f2bf(v0.x); o.s[1] = f2bf(v0.y); o.s[2] = f2bf(v0.z); o.s[3] = f2bf(v0.w);
  o.s[4] = f2bf(v1.x); o.s[5] = f2bf(v1.y); o.s[6] = f2bf(v1.z); o.s[7] = f2bf(v1.w);
  *(u32x4*)(Apack + base) = o.v;
}

// ---- prep 2: Wt[g][n][k] = bf16( k<1024 ? Wx[g][k][n] : Wh[g][k-1024][n] ) ----
__global__ __launch_bounds__(256) void prep_w_kernel(
    const float* __restrict__ Wx, const float* __restrict__ Wh,
    unsigned short* __restrict__ Wt) {
  __shared__ float tile[32][33];
  int bid = blockIdx.x;
  int g = bid >> 11;
  int rem = bid & 2047;
  int kt = rem >> 5;
  int nt = rem & 31;
  int k0 = kt * 32, n0 = nt * 32;
  int tx = threadIdx.x & 31, ty = threadIdx.x >> 5;
  const float* Wsrc;
  int ks;
  if (k0 < 1024) { Wsrc = Wx + (size_t)g * 1048576; ks = k0; }
  else           { Wsrc = Wh + (size_t)g * 1048576; ks = k0 - 1024; }
  #pragma unroll
  for (int s = 0; s < 4; ++s) {
    int r = ty + s * 8;
    tile[r][tx] = Wsrc[(size_t)(ks + r) * 1024 + n0 + tx];
  }
  __syncthreads();
  #pragma unroll
  for (int s = 0; s < 4; ++s) {
    int r = ty + s * 8;
    Wt[(size_t)((g << 10) + n0 + r) * 2048 + k0 + tx] = f2bf(tile[tx][r]);
  }
}

// ---- main: fused 4-gate GEMM, 8-phase schedule ----
// 512 thr = 8 waves (wr: rows wr*128..+128; wc: n wc*16..+16 per gate).
// Buf (64KB): A[256][64] @0 (A0 rows 0-127, A1 128-255), B[4][64][64] @32768
// (B0 g0-1, B1 g2-3). Stage plan per K-step t: P1 A1(t+1)->bufn,
// P2 B0(t+2)->bufc, P3 B1(t+2)->bufc, P4 A0(t+2)->bufc. One vmcnt(6)/K-step.
__global__ __launch_bounds__(512, 2) void lstm_gemm_kernel(
    const unsigned short* __restrict__ Apack,   // [8192][2048] bf16
    const unsigned short* __restrict__ Wt,      // [4][1024][2048] bf16 (B^T)
    const float* __restrict__ cprev,
    float* __restrict__ out) {
  extern __shared__ char lds[];
  const int tid = threadIdx.x;
  const int l = tid & 63;
  const int w = tid >> 6;
  const int wr = w >> 2;
  const int wc = w & 3;
  const int bid0 = blockIdx.x;
  const int bid = (bid0 & 7) * 64 + (bid0 >> 3);   // XCD chunk swizzle (512%8==0)
  const int mt = bid >> 4;             // 32 m-tiles
  const int nt = bid & 15;             // 16 n-tiles
  const int m0 = mt << 8;
  const int n0 = nt << 6;

  char* const buf0 = lds;
  char* const buf1 = lds + 65536;

  f32x4 acc[8][4];                     // [m-frag][gate]
  #pragma unroll
  for (int mf = 0; mf < 8; ++mf)
    #pragma unroll
    for (int g = 0; g < 4; ++g) acc[mf][g] = (f32x4)0.0f;

  bf16x8 aR[4][2];                     // current m-half frags [i][kk]
  bf16x8 bR[4][2];                     // all gates [g][kk]

  const int lr = l & 15;
  const int kgrp = (l >> 4) << 4;      // 0/16/32/48 byte k-group
  const int sx = (lr & 7) << 4;        // XOR swizzle (row&7 == lr&7 everywhere)
  const int kx0 = kgrp ^ sx;           // precomputed swizzled k-offsets
  const int kx1 = (64 + kgrp) ^ sx;
  const int aoff = (wr * 128 + lr) * 128;
  const int boff = 32768 + (wc * 16 + lr) * 128;

  // Hoisted stage bases. A: chunk c = j*512+tid -> row c/8 = j*64 + tid/8,
  // kb = ((tid&7)<<4) ^ (((tid>>3)&7)<<4) — depends only on tid (j*64, h*128
  // are 0 mod 8). One base pointer; h delta = 128 rows = 262144 elem,
  // j delta = 64 rows = 131072 elem.
  const int arl = tid >> 3;                          // row for h=0,j=0
  const int akb = ((tid << 4) & 127) ^ ((arl & 7) << 4);
  const unsigned short* const gAbase =
      Apack + (size_t)(m0 + arl) * 2048 + (akb >> 1);
  const int dAbase = (tid & ~63) << 4;               // LDS dest, h=0,j=0
  // B: gate = 2h+j (delta = 2097152 elem/gate), row rl = tid>>3 within gate.
  const unsigned short* const gBbase =
      Wt + (size_t)(n0 + arl) * 2048 + (akb >> 1);
  const int dBbase = 32768 + ((tid & ~63) << 4);

  auto stageA = [&](char* bufb, int h, int kstep) {
    const unsigned short* g0 = gAbase + ((size_t)h * 262144 + (kstep << 6));
    #pragma unroll
    for (int j = 0; j < 2; ++j)
      load16(g0 + (size_t)j * 131072,              // +64 rows * 2048
             bufb + dAbase + h * 16384 + j * 8192);
  };
  auto stageB = [&](char* bufb, int h, int kstep) {
    const unsigned short* g0 = gBbase + ((size_t)(2 * h) * 2097152 + (kstep << 6));
    #pragma unroll
    for (int j = 0; j < 2; ++j)
      load16(g0 + (size_t)j * 2097152,             // +1 gate * 1024*2048
             bufb + dBbase + h * 16384 + j * 8192);
  };

  auto readA = [&](const char* bufc, int mh) {   // 8 ds_read_b128
    #pragma unroll
    for (int i = 0; i < 4; ++i) {
      const char* p = bufc + aoff + (mh * 64 + i * 16) * 128;
      aR[i][0] = *(const bf16x8*)(p + kx0);
      aR[i][1] = *(const bf16x8*)(p + kx1);
    }
  };
  auto readB = [&](const char* bufc, int gh) {   // 4 ds_read_b128
    #pragma unroll
    for (int i = 0; i < 2; ++i) {
      const char* p = bufc + boff + (gh * 2 + i) * 8192;
      bR[gh * 2 + i][0] = *(const bf16x8*)(p + kx0);
      bR[gh * 2 + i][1] = *(const bf16x8*)(p + kx1);
    }
  };
  auto mfma16 = [&](int mh, int gh) {            // one C-quadrant x K=64
    __builtin_amdgcn_s_setprio(1);
    #pragma unroll
    for (int kk = 0; kk < 2; ++kk)
      #pragma unroll
      for (int i = 0; i < 4; ++i)
        #pragma unroll
        for (int gg = 0; gg < 2; ++gg)
          acc[mh * 4 + i][gh * 2 + gg] = __builtin_amdgcn_mfma_f32_16x16x32_bf16(
              aR[i][kk], bR[gh * 2 + gg][kk], acc[mh * 4 + i][gh * 2 + gg], 0, 0, 0);
    __builtin_amdgcn_s_setprio(0);
  };

  // Prologue: stage t=0's 4 halves + t=1's {B0,B1,A0}; vmcnt(6) -> t=0 landed.
  stageA(buf0, 0, 0); stageA(buf0, 1, 0);
  stageB(buf0, 0, 0); stageB(buf0, 1, 0);
  stageB(buf1, 0, 1); stageB(buf1, 1, 1);
  stageA(buf1, 0, 1);
  asm volatile("s_waitcnt vmcnt(6)" ::: "memory");
  __builtin_amdgcn_s_barrier();

  auto kstep = [&](int t, char* bufc, char* bufn) {
    // ---- P1: quad (mh0, gh0) ----
    readA(bufc, 0);
    readB(bufc, 0);
    if (t + 1 < 32) stageA(bufn, 1, t + 1);      // A1(t+1)
    asm volatile("s_waitcnt lgkmcnt(8)" ::: "memory");
    __builtin_amdgcn_s_barrier();
    asm volatile("s_waitcnt lgkmcnt(0)" ::: "memory");
    mfma16(0, 0);
    __builtin_amdgcn_s_barrier();
    // ---- P2: quad (mh0, gh1) ----
    readB(bufc, 1);
    if (t + 2 < 32) stageB(bufc, 0, t + 2);      // B0(t+2): B0 reads done @P1
    __builtin_amdgcn_s_barrier();
    asm volatile("s_waitcnt lgkmcnt(0)" ::: "memory");
    mfma16(0, 1);
    __builtin_amdgcn_s_barrier();
    // ---- P3: quad (mh1, gh1) ----
    readA(bufc, 1);
    if (t + 2 < 32) stageB(bufc, 1, t + 2);      // B1(t+2): B1 reads done @P2
    __builtin_amdgcn_s_barrier();
    asm volatile("s_waitcnt lgkmcnt(0)" ::: "memory");
    mfma16(1, 1);
    __builtin_amdgcn_s_barrier();
    // ---- P4: quad (mh1, gh0) ---- (no ds_reads; bR[g0,g1] live from P1)
    if (t + 2 < 32) stageA(bufc, 0, t + 2);      // A0(t+2): A0 reads done @P3
    if (t < 30) asm volatile("s_waitcnt vmcnt(6)" ::: "memory");
    else        asm volatile("s_waitcnt vmcnt(0)" ::: "memory");
    __builtin_amdgcn_s_barrier();                // all waves: t+1 halves landed
    mfma16(1, 0);
    __builtin_amdgcn_s_barrier();
  };

  #pragma unroll 1
  for (int tt = 0; tt < 16; ++tt) {
    kstep(2 * tt,     buf0, buf1);
    kstep(2 * tt + 1, buf1, buf0);
  }

  // Epilogue: C/D layout col = lane&15, row = (lane>>4)*4 + reg  [m89]
  const int q = (l >> 4) << 2;
  const int col = n0 + wc * 16 + lr;
  #pragma unroll
  for (int mf = 0; mf < 8; ++mf) {
    #pragma unroll
    for (int j = 0; j < 4; ++j) {
      int row = m0 + wr * 128 + mf * 16 + q + j;
      float gi = acc[mf][0][j];
      float gf = acc[mf][1][j];
      float go = acc[mf][2][j];
      float gu = acc[mf][3][j];
      float i_ = sigmoid_f(gi);
      float f_ = sigmoid_f(gf);
      float o_ = sigmoid_f(go);
      float u_ = tanh_f(gu);
      size_t idx = (size_t)row * 1024 + col;
      float ct = i_ * u_ + f_ * cprev[idx];
      float ht = o_ * tanh_f(ct);
      out[idx] = ht;                   // h_t
      out[8388608 + idx] = ct;         // c_t
    }
  }
}

extern "C" void kernel_launch(void* const* d_in, const int* in_sizes, int n_in,
                              void* d_out, int out_size, void* d_ws, size_t ws_size,
                              hipStream_t stream) {
  const float* x  = (const float*)d_in[0];
  const float* h  = (const float*)d_in[1];
  const float* c  = (const float*)d_in[2];
  const float* Wx = (const float*)d_in[3];
  const float* Wh = (const float*)d_in[4];
  float* out = (float*)d_out;

  unsigned short* Apack = (unsigned short*)d_ws;                  // 33,554,432 B
  unsigned short* Wt = (unsigned short*)((char*)d_ws + 33554432); // 16,777,216 B

  hipFuncSetAttribute((const void*)lstm_gemm_kernel,
                      hipFuncAttributeMaxDynamicSharedMemorySize, LDS_TOTAL);

  pack_a_kernel<<<8192, 256, 0, stream>>>(x, h, Apack);
  prep_w_kernel<<<8192, 256, 0, stream>>>(Wx, Wh, Wt);
  lstm_gemm_kernel<<<dim3(512), dim3(512), LDS_TOTAL, stream>>>(Apack, Wt, c, out);
}